// Round 13
// baseline (308.304 us; speedup 1.0000x reference)
//
#include <hip/hip_runtime.h>
#include <stdint.h>

#define IMG  512
#define CPT  8
#define CGRP (IMG / CPT)    // 64 col-groups per row
#define NROWS 16384         // 32 batches * 512 rows

// ---- shared helpers -------------------------------------------------------

// Load rows y-1,y,y+1 of logical row index `row` (b*IMG+y), cols x0-1..x0+8,
// zero-padded outside. Array-reference form (SROA-safe).
__device__ __forceinline__ void load3(const float* __restrict__ x, int row,
                                      int x0, bool has_l, bool has_r,
                                      float (&r0)[10], float (&r1)[10],
                                      float (&r2)[10]) {
    const int y = row & (IMG - 1);
    const float* xr = x + (size_t)row * IMG;
    auto load_row = [&](const float* p, float (&r)[10]) {
        float4 a = *reinterpret_cast<const float4*>(p + x0);
        float4 c = *reinterpret_cast<const float4*>(p + x0 + 4);
        r[1] = a.x; r[2] = a.y; r[3] = a.z; r[4] = a.w;
        r[5] = c.x; r[6] = c.y; r[7] = c.z; r[8] = c.w;
        r[0] = has_l ? p[x0 - 1] : 0.0f;
        r[9] = has_r ? p[x0 + 8] : 0.0f;
    };
    auto zero_row = [&](float (&r)[10]) {
#pragma unroll
        for (int k = 0; k < 10; ++k) r[k] = 0.0f;
    };
    if (y > 0)       load_row(xr - IMG, r0); else zero_row(r0);
                     load_row(xr,       r1);
    if (y < IMG - 1) load_row(xr + IMG, r2); else zero_row(r2);
}

// ---- REAL kernel (identical math to R12: scalar f32 conv + LDS LUT) -------

__global__ __launch_bounds__(256) void fused_convtap_kernel(
    const float* __restrict__ x, const float* __restrict__ W,
    const float* __restrict__ Bv, float* __restrict__ out)
{
    __shared__ float lut[4096];
#pragma unroll
    for (int k = 0; k < 16; ++k) {
        const int i  = threadIdx.x + (k << 8);
        const float xi = fmaf((float)i, 0.001953125f, 0.0009765625f - 4.0f);
        const float e  = __builtin_amdgcn_exp2f(xi * 2.8853900817779268f);
        lut[i] = 1.0f - 2.0f * __builtin_amdgcn_rcpf(e + 1.0f);
    }
    __syncthreads();

    const int tid = blockIdx.x * 256 + threadIdx.x;
    const int xg  = tid & (CGRP - 1);
    const int row = tid >> 6;
    const int x0  = xg * CPT;

    float w[81];
#pragma unroll
    for (int k = 0; k < 81; ++k) w[k] = W[k];
    float bv[9];
#pragma unroll
    for (int c = 0; c < 9; ++c) bv[c] = Bv[c];

    const bool has_l = (x0 > 0);
    const bool has_r = (x0 < IMG - CPT);

    float r0[10], r1[10], r2[10];
    load3(x, row, x0, has_l, has_r, r0, r1, r2);

    auto tlu = [&](float v) -> float {
        float t = __builtin_amdgcn_fmed3f(fmaf(v, 512.0f, 2048.0f),
                                          0.0f, 4095.0f);
        return lut[(int)t];
    };

#define RSEL(p, idx) ((p) == 0 ? r0[idx] : (p) == 1 ? r1[idx] : r2[idx])
    float o[CPT];
#pragma unroll
    for (int t = 0; t < CPT; ++t) {
        float acc = 0.0f;
#pragma unroll
        for (int i = 0; i < 3; ++i) {
#pragma unroll
            for (int j = 0; j < 3; ++j) {
                const int c = 3 * i + j;
                float fc = bv[c];
#pragma unroll
                for (int p = 0; p < 3; ++p)
#pragma unroll
                    for (int q = 0; q < 3; ++q)
                        fc = fmaf(RSEL(p, t + q), w[c * 9 + p * 3 + q], fc);
                acc = fmaf(RSEL(j, t + i), tlu(fc), acc);
            }
        }
        o[t] = acc;
    }
#undef RSEL

    float* orow = out + (size_t)row * IMG + x0;
    *reinterpret_cast<float4*>(orow)     = make_float4(o[0], o[1], o[2], o[3]);
    *reinterpret_cast<float4*>(orow + 4) = make_float4(o[4], o[5], o[6], o[7]);
}

// ---- DIAGNOSTIC 1: memory path only (x6 reps over distinct regions) -------

__global__ __launch_bounds__(256) void k_copy(
    const float* __restrict__ x, float* __restrict__ ws)
{
    const int tid = blockIdx.x * 256 + threadIdx.x;
    const int xg  = tid & (CGRP - 1);
    const int row = tid >> 6;
    const int x0  = xg * CPT;
    const bool has_l = (x0 > 0);
    const bool has_r = (x0 < IMG - CPT);

    float o[CPT] = {0, 0, 0, 0, 0, 0, 0, 0};
#pragma unroll
    for (int rep = 0; rep < 6; ++rep) {
        const int row2 = (row + rep * 2730) & (NROWS - 1);
        float r0[10], r1[10], r2[10];
        load3(x, row2, x0, has_l, has_r, r0, r1, r2);
#pragma unroll
        for (int t = 0; t < CPT; ++t) o[t] += r0[t] + r1[t] + r2[t];
        o[0] += r0[8] + r0[9] + r1[8] + r1[9] + r2[8] + r2[9];
    }
    float* orow = ws + (size_t)row * IMG + x0;
    *reinterpret_cast<float4*>(orow)     = make_float4(o[0], o[1], o[2], o[3]);
    *reinterpret_cast<float4*>(orow + 4) = make_float4(o[4], o[5], o[6], o[7]);
}

// ---- DIAGNOSTIC 2: loads + f32 conv only (x3 reps) ------------------------

__global__ __launch_bounds__(256) void k_conv(
    const float* __restrict__ x, const float* __restrict__ W,
    const float* __restrict__ Bv, float* __restrict__ ws)
{
    const int tid = blockIdx.x * 256 + threadIdx.x;
    const int xg  = tid & (CGRP - 1);
    const int row = tid >> 6;
    const int x0  = xg * CPT;
    const bool has_l = (x0 > 0);
    const bool has_r = (x0 < IMG - CPT);

    float w[81];
#pragma unroll
    for (int k = 0; k < 81; ++k) w[k] = W[k];
    float bv[9];
#pragma unroll
    for (int c = 0; c < 9; ++c) bv[c] = Bv[c];

    float o[CPT] = {0, 0, 0, 0, 0, 0, 0, 0};
#pragma unroll
    for (int rep = 0; rep < 3; ++rep) {
        const int row2 = (row + rep * 5461) & (NROWS - 1);
        float r0[10], r1[10], r2[10];
        load3(x, row2, x0, has_l, has_r, r0, r1, r2);
#define RSEL(p, idx) ((p) == 0 ? r0[idx] : (p) == 1 ? r1[idx] : r2[idx])
#pragma unroll
        for (int t = 0; t < CPT; ++t) {
            float acc = 0.0f;
#pragma unroll
            for (int c = 0; c < 9; ++c) {
                float fc = bv[c];
                const int ci = c / 3;  // reuse i/j decomposition
#pragma unroll
                for (int p = 0; p < 3; ++p)
#pragma unroll
                    for (int q = 0; q < 3; ++q)
                        fc = fmaf(RSEL(p, t + q), w[c * 9 + p * 3 + q], fc);
                acc += fc + (float)ci * 0.0f;
            }
            o[t] += acc;
        }
#undef RSEL
    }
    float* orow = ws + (size_t)row * IMG + x0;
    *reinterpret_cast<float4*>(orow)     = make_float4(o[0], o[1], o[2], o[3]);
    *reinterpret_cast<float4*>(orow + 4) = make_float4(o[4], o[5], o[6], o[7]);
}

// ---- DIAGNOSTIC 3: loads + LDS LUT lookups only (x3 reps) -----------------

__global__ __launch_bounds__(256) void k_lut(
    const float* __restrict__ x, const float* __restrict__ Bv,
    float* __restrict__ ws)
{
    __shared__ float lut[4096];
#pragma unroll
    for (int k = 0; k < 16; ++k) {
        const int i  = threadIdx.x + (k << 8);
        const float xi = fmaf((float)i, 0.001953125f, 0.0009765625f - 4.0f);
        const float e  = __builtin_amdgcn_exp2f(xi * 2.8853900817779268f);
        lut[i] = 1.0f - 2.0f * __builtin_amdgcn_rcpf(e + 1.0f);
    }
    __syncthreads();

    const int tid = blockIdx.x * 256 + threadIdx.x;
    const int xg  = tid & (CGRP - 1);
    const int row = tid >> 6;
    const int x0  = xg * CPT;
    const bool has_l = (x0 > 0);
    const bool has_r = (x0 < IMG - CPT);

    float bv[9];
#pragma unroll
    for (int c = 0; c < 9; ++c) bv[c] = Bv[c];

    auto tlu = [&](float v) -> float {
        float t = __builtin_amdgcn_fmed3f(fmaf(v, 512.0f, 2048.0f),
                                          0.0f, 4095.0f);
        return lut[(int)t];
    };

    float o[CPT] = {0, 0, 0, 0, 0, 0, 0, 0};
#pragma unroll
    for (int rep = 0; rep < 3; ++rep) {
        const int row2 = (row + rep * 5461) & (NROWS - 1);
        float r0[10], r1[10], r2[10];
        load3(x, row2, x0, has_l, has_r, r0, r1, r2);
#pragma unroll
        for (int t = 0; t < CPT; ++t) {
            float acc = 0.0f;
#pragma unroll
            for (int c = 0; c < 9; ++c)
                acc += tlu(fmaf(r1[t + 1], bv[c], r0[t]));
            o[t] += acc;
        }
    }
    float* orow = ws + (size_t)row * IMG + x0;
    *reinterpret_cast<float4*>(orow)     = make_float4(o[0], o[1], o[2], o[3]);
    *reinterpret_cast<float4*>(orow + 4) = make_float4(o[4], o[5], o[6], o[7]);
}

// ---- launch ---------------------------------------------------------------

extern "C" void kernel_launch(void* const* d_in, const int* in_sizes, int n_in,
                              void* d_out, int out_size, void* d_ws, size_t ws_size,
                              hipStream_t stream) {
    const float* x  = (const float*)d_in[0];
    const float* W  = (const float*)d_in[1];
    const float* Bv = (const float*)d_in[2];
    float* out = (float*)d_out;
    float* ws  = (float*)d_ws;

    const int batch   = in_sizes[0] / (IMG * IMG);   // 32
    const int threads = batch * IMG * CGRP;          // 1,048,576
    const int grid    = threads / 256;               // 4096

    // Real kernel first (graded output, counters comparable to R12).
    fused_convtap_kernel<<<grid, 256, 0, stream>>>(x, W, Bv, out);

    // Ablation diagnostics (write scratch only; per-dispatch rocprof rows).
    if (ws_size >= (size_t)threads * CPT * sizeof(float)) {
        k_copy<<<grid, 256, 0, stream>>>(x, ws);
        k_conv<<<grid, 256, 0, stream>>>(x, W, Bv, ws);
        k_lut <<<grid, 256, 0, stream>>>(x, Bv, ws);
    }
}

// Round 14
// 264.130 us; speedup vs baseline: 1.1672x; 1.1672x over previous
//
#include <hip/hip_runtime.h>
#include <stdint.h>

#define IMG  512
#define CPT  8
#define CGRP (IMG / CPT)    // 64 col-groups per row

typedef _Float16 h2    __attribute__((ext_vector_type(2)));
typedef __fp16   f16x2 __attribute__((ext_vector_type(2)));

static __device__ __forceinline__ h2 pkrtz(float a, float b) {
    f16x2 t = __builtin_amdgcn_cvt_pkrtz(a, b);
    return __builtin_bit_cast(h2, t);
}

#if __has_builtin(__builtin_amdgcn_fdot2)
#define FDOT2(a, b, c) __builtin_amdgcn_fdot2((a), (b), (c), false)
#else
static __device__ __forceinline__ float fdot2_sw(h2 a, h2 b, float c) {
    return fmaf((float)a.x, (float)b.x, fmaf((float)a.y, (float)b.y, c));
}
#define FDOT2(a, b, c) fdot2_sw((a), (b), (c))
#endif

// Load rows y-1,y,y+1, cols x0-1..x0+8, zero-padded (SROA-safe references).
__device__ __forceinline__ void load3(const float* __restrict__ x, int row,
                                      int x0, bool has_l, bool has_r,
                                      float (&r0)[10], float (&r1)[10],
                                      float (&r2)[10]) {
    const int y = row & (IMG - 1);
    const float* xr = x + (size_t)row * IMG;
    auto load_row = [&](const float* p, float (&r)[10]) {
        float4 a = *reinterpret_cast<const float4*>(p + x0);
        float4 c = *reinterpret_cast<const float4*>(p + x0 + 4);
        r[1] = a.x; r[2] = a.y; r[3] = a.z; r[4] = a.w;
        r[5] = c.x; r[6] = c.y; r[7] = c.z; r[8] = c.w;
        r[0] = has_l ? p[x0 - 1] : 0.0f;
        r[9] = has_r ? p[x0 + 8] : 0.0f;
    };
    auto zero_row = [&](float (&r)[10]) {
#pragma unroll
        for (int k = 0; k < 10; ++k) r[k] = 0.0f;
    };
    if (y > 0)       load_row(xr - IMG, r0); else zero_row(r0);
                     load_row(xr,       r1);
    if (y < IMG - 1) load_row(xr + IMG, r2); else zero_row(r2);
}

#define FILL_LUT(lut)                                                        \
    {                                                                        \
        _Pragma("unroll")                                                    \
        for (int k = 0; k < 16; ++k) {                                       \
            const int i  = threadIdx.x + (k << 8);                           \
            const float xi = fmaf((float)i, 0.001953125f,                    \
                                  0.0009765625f - 4.0f);                     \
            const float e  = __builtin_amdgcn_exp2f(xi * 2.8853900817779268f);\
            lut[i] = 1.0f - 2.0f * __builtin_amdgcn_rcpf(e + 1.0f);          \
        }                                                                    \
    }

// ---- A: REAL kernel (exact R12: scalar f32 conv + LDS LUT, graded) --------

__global__ __launch_bounds__(256) void fused_convtap_kernel(
    const float* __restrict__ x, const float* __restrict__ W,
    const float* __restrict__ Bv, float* __restrict__ out)
{
    __shared__ float lut[4096];
    FILL_LUT(lut);
    __syncthreads();

    const int tid = blockIdx.x * 256 + threadIdx.x;
    const int xg  = tid & (CGRP - 1);
    const int row = tid >> 6;
    const int x0  = xg * CPT;

    float w[81];
#pragma unroll
    for (int k = 0; k < 81; ++k) w[k] = W[k];
    float bv[9];
#pragma unroll
    for (int c = 0; c < 9; ++c) bv[c] = Bv[c];

    const bool has_l = (x0 > 0);
    const bool has_r = (x0 < IMG - CPT);
    float r0[10], r1[10], r2[10];
    load3(x, row, x0, has_l, has_r, r0, r1, r2);

    auto tlu = [&](float v) -> float {
        float t = __builtin_amdgcn_fmed3f(fmaf(v, 512.0f, 2048.0f),
                                          0.0f, 4095.0f);
        return lut[(int)t];
    };

#define RSEL(p, idx) ((p) == 0 ? r0[idx] : (p) == 1 ? r1[idx] : r2[idx])
    float o[CPT];
#pragma unroll
    for (int t = 0; t < CPT; ++t) {
        float acc = 0.0f;
#pragma unroll
        for (int i = 0; i < 3; ++i) {
#pragma unroll
            for (int j = 0; j < 3; ++j) {
                const int c = 3 * i + j;
                float fc = bv[c];
#pragma unroll
                for (int p = 0; p < 3; ++p)
#pragma unroll
                    for (int q = 0; q < 3; ++q)
                        fc = fmaf(RSEL(p, t + q), w[c * 9 + p * 3 + q], fc);
                acc = fmaf(RSEL(j, t + i), tlu(fc), acc);
            }
        }
        o[t] = acc;
    }
#undef RSEL

    float* orow = out + (size_t)row * IMG + x0;
    *reinterpret_cast<float4*>(orow)     = make_float4(o[0], o[1], o[2], o[3]);
    *reinterpret_cast<float4*>(orow + 4) = make_float4(o[4], o[5], o[6], o[7]);
}

// ---- B: IDENTICAL body, compute x5 on the SAME rows (slope probe) ---------
// #pragma unroll 1 + strict-FP bias scale: no load duplication, no hoisting,
// no CSE across reps. slope_f32 = (durB - durA)/4 at A's own occupancy.

__global__ __launch_bounds__(256) void k_rep_f32(
    const float* __restrict__ x, const float* __restrict__ W,
    const float* __restrict__ Bv, float* __restrict__ ws)
{
    __shared__ float lut[4096];
    FILL_LUT(lut);
    __syncthreads();

    const int tid = blockIdx.x * 256 + threadIdx.x;
    const int xg  = tid & (CGRP - 1);
    const int row = tid >> 6;
    const int x0  = xg * CPT;

    float w[81];
#pragma unroll
    for (int k = 0; k < 81; ++k) w[k] = W[k];
    float bv[9];
#pragma unroll
    for (int c = 0; c < 9; ++c) bv[c] = Bv[c];

    const bool has_l = (x0 > 0);
    const bool has_r = (x0 < IMG - CPT);
    float r0[10], r1[10], r2[10];
    load3(x, row, x0, has_l, has_r, r0, r1, r2);

    auto tlu = [&](float v) -> float {
        float t = __builtin_amdgcn_fmed3f(fmaf(v, 512.0f, 2048.0f),
                                          0.0f, 4095.0f);
        return lut[(int)t];
    };

#define RSEL(p, idx) ((p) == 0 ? r0[idx] : (p) == 1 ? r1[idx] : r2[idx])
    float o[CPT] = {0, 0, 0, 0, 0, 0, 0, 0};
#pragma unroll 1
    for (int rep = 0; rep < 5; ++rep) {
        const float s = 1.0f + 1.0e-7f * (float)rep;
#pragma unroll
        for (int t = 0; t < CPT; ++t) {
            float acc = 0.0f;
#pragma unroll
            for (int i = 0; i < 3; ++i) {
#pragma unroll
                for (int j = 0; j < 3; ++j) {
                    const int c = 3 * i + j;
                    float fc = bv[c] * s;
#pragma unroll
                    for (int p = 0; p < 3; ++p)
#pragma unroll
                        for (int q = 0; q < 3; ++q)
                            fc = fmaf(RSEL(p, t + q), w[c * 9 + p * 3 + q], fc);
                    acc = fmaf(RSEL(j, t + i), tlu(fc), acc);
                }
            }
            o[t] += acc;
        }
    }
#undef RSEL

    float* orow = ws + (size_t)row * IMG + x0;
    *reinterpret_cast<float4*>(orow)     = make_float4(o[0], o[1], o[2], o[3]);
    *reinterpret_cast<float4*>(orow + 4) = make_float4(o[4], o[5], o[6], o[7]);
}

// ---- C: dot2-conv formulation x5 (within-probe packed-rate test) ----------

__global__ __launch_bounds__(256) void k_rep_dot2(
    const float* __restrict__ x, const float* __restrict__ W,
    const float* __restrict__ Bv, float* __restrict__ ws)
{
    __shared__ float lut[4096];
    FILL_LUT(lut);
    __syncthreads();

    const int tid = blockIdx.x * 256 + threadIdx.x;
    const int xg  = tid & (CGRP - 1);
    const int row = tid >> 6;
    const int x0  = xg * CPT;

    h2 u[9][4];
    float w8[9], bv[9];
#pragma unroll
    for (int c = 0; c < 9; ++c) {
#pragma unroll
        for (int k = 0; k < 4; ++k)
            u[c][k] = pkrtz(W[c * 9 + 2 * k], W[c * 9 + 2 * k + 1]);
        w8[c] = W[c * 9 + 8];
        bv[c] = Bv[c];
    }

    const bool has_l = (x0 > 0);
    const bool has_r = (x0 < IMG - CPT);
    float r0[10], r1[10], r2[10];
    load3(x, row, x0, has_l, has_r, r0, r1, r2);

    auto tlu = [&](float v) -> float {
        float t = __builtin_amdgcn_fmed3f(fmaf(v, 512.0f, 2048.0f),
                                          0.0f, 4095.0f);
        return lut[(int)t];
    };

    float o[CPT] = {0, 0, 0, 0, 0, 0, 0, 0};
#pragma unroll 1
    for (int rep = 0; rep < 5; ++rep) {
        const float s = 1.0f + 1.0e-7f * (float)rep;
#pragma unroll
        for (int tp = 0; tp < 4; ++tp) {
            const int t0 = 2 * tp;
            h2 A0 = pkrtz(r0[t0],     r0[t0 + 1]);
            h2 B0 = pkrtz(r0[t0 + 2], r1[t0]);
            h2 C0 = pkrtz(r1[t0 + 1], r1[t0 + 2]);
            h2 D0 = pkrtz(r2[t0],     r2[t0 + 1]);
            h2 A1 = pkrtz(r0[t0 + 1], r0[t0 + 2]);
            h2 B1 = pkrtz(r0[t0 + 3], r1[t0 + 1]);
            h2 C1 = pkrtz(r1[t0 + 2], r1[t0 + 3]);
            h2 D1 = pkrtz(r2[t0 + 1], r2[t0 + 2]);

            float ox = 0.0f, oy = 0.0f;
#pragma unroll
            for (int c = 0; c < 9; ++c) {
                float fx = bv[c] * s, fy = bv[c] * s;
                fx = FDOT2(A0, u[c][0], fx);
                fy = FDOT2(A1, u[c][0], fy);
                fx = FDOT2(B0, u[c][1], fx);
                fy = FDOT2(B1, u[c][1], fy);
                fx = FDOT2(C0, u[c][2], fx);
                fy = FDOT2(C1, u[c][2], fy);
                fx = FDOT2(D0, u[c][3], fx);
                fy = FDOT2(D1, u[c][3], fy);
                fx = fmaf(r2[t0 + 2], w8[c], fx);
                fy = fmaf(r2[t0 + 3], w8[c], fy);

                const float thx = tlu(fx);
                const float thy = tlu(fy);
                const int i = c / 3, j = c - 3 * i;
                const float* rj = (j == 0) ? r0 : (j == 1) ? r1 : r2;
                ox = fmaf(rj[t0 + i],     thx, ox);
                oy = fmaf(rj[t0 + 1 + i], thy, oy);
            }
            o[t0] += ox; o[t0 + 1] += oy;
        }
    }

    float* orow = ws + (size_t)row * IMG + x0;
    *reinterpret_cast<float4*>(orow)     = make_float4(o[0], o[1], o[2], o[3]);
    *reinterpret_cast<float4*>(orow + 4) = make_float4(o[4], o[5], o[6], o[7]);
}

// ---- launch ---------------------------------------------------------------

extern "C" void kernel_launch(void* const* d_in, const int* in_sizes, int n_in,
                              void* d_out, int out_size, void* d_ws, size_t ws_size,
                              hipStream_t stream) {
    const float* x  = (const float*)d_in[0];
    const float* W  = (const float*)d_in[1];
    const float* Bv = (const float*)d_in[2];
    float* out = (float*)d_out;
    float* ws  = (float*)d_ws;

    const int batch   = in_sizes[0] / (IMG * IMG);   // 32
    const int threads = batch * IMG * CGRP;          // 1,048,576
    const int grid    = threads / 256;               // 4096

    fused_convtap_kernel<<<grid, 256, 0, stream>>>(x, W, Bv, out);

    if (ws_size >= (size_t)threads * CPT * sizeof(float)) {
        k_rep_f32 <<<grid, 256, 0, stream>>>(x, W, Bv, ws);
        k_rep_dot2<<<grid, 256, 0, stream>>>(x, W, Bv, ws);
    }
}

// Round 15
// 34.786 us; speedup vs baseline: 8.8629x; 7.5930x over previous
//
#include <hip/hip_runtime.h>
#include <stdint.h>

#define IMG  512
#define CPT  8
#define CGRP (IMG / CPT)    // 64 col-groups per row

typedef _Float16 h2    __attribute__((ext_vector_type(2)));
typedef __fp16   f16x2 __attribute__((ext_vector_type(2)));

static __device__ __forceinline__ h2 pkrtz(float a, float b) {
    f16x2 t = __builtin_amdgcn_cvt_pkrtz(a, b);   // v_cvt_pkrtz_f16_f32
    return __builtin_bit_cast(h2, t);
}

#if __has_builtin(__builtin_amdgcn_fdot2)
#define FDOT2(a, b, c) __builtin_amdgcn_fdot2((a), (b), (c), false)
#else
static __device__ __forceinline__ float fdot2_sw(h2 a, h2 b, float c) {
    return fmaf((float)a.x, (float)b.x, fmaf((float)a.y, (float)b.y, c));
}
#define FDOT2(a, b, c) fdot2_sw((a), (b), (c))
#endif

// R14 slope probe: dot2-conv body ~10-13us/iter vs scalar-f32 ~25us/iter;
// intercept ~16us of which LUT fill was ~5us. This kernel = dot2 conv +
// 2048-entry LDS LUT tanh + geometric LUT fill + loads-issued-before-fill.
//
// LUT: entry i = tanh((i+0.5)/256 - 4), i=0..2047 (step 1/256 on [-4,4]);
// nearest-neighbor err <= 2e-3; clamped tails err <= 6.7e-4.
// Geometric fill: x_{i+256} = x_i + 1  =>  e_{i+256} = e_i * e^2
// (e = exp2(2*log2e*x)), so 8 entries = 1 exp2 + 7 mul + 8 rcp.

__global__ __launch_bounds__(256) void fused_convtap_kernel(
    const float* __restrict__ x,   // (B,1,512,512)
    const float* __restrict__ W,   // (9,1,3,3)
    const float* __restrict__ Bv,  // (9,)
    float* __restrict__ out)       // (B,1,512,512)
{
    __shared__ float lut[2048];

    const int tid = blockIdx.x * 256 + threadIdx.x;
    const int xg  = tid & (CGRP - 1);
    const int row = tid >> 6;            // b*IMG + y
    const int y   = row & (IMG - 1);
    const int x0  = xg * CPT;

    const float* xr = x + (size_t)row * IMG;
    const bool has_l = (x0 > 0);
    const bool has_r = (x0 < IMG - CPT);

    // ---- issue global row loads FIRST: HBM latency hides under LUT fill ----
    float r0[10], r1[10], r2[10];
    {
        auto load_row = [&](const float* p, float (&r)[10]) {
            float4 a = *reinterpret_cast<const float4*>(p + x0);
            float4 c = *reinterpret_cast<const float4*>(p + x0 + 4);
            r[1] = a.x; r[2] = a.y; r[3] = a.z; r[4] = a.w;
            r[5] = c.x; r[6] = c.y; r[7] = c.z; r[8] = c.w;
            r[0] = has_l ? p[x0 - 1] : 0.0f;
            r[9] = has_r ? p[x0 + 8] : 0.0f;
        };
        auto zero_row = [&](float (&r)[10]) {
#pragma unroll
            for (int k = 0; k < 10; ++k) r[k] = 0.0f;
        };
        if (y > 0)       load_row(xr - IMG, r0); else zero_row(r0);
                         load_row(xr,       r1);
        if (y < IMG - 1) load_row(xr + IMG, r2); else zero_row(r2);
    }

    // ---- geometric LUT fill (8 entries/thread, stride 256) ----
    {
        const float E2 = 7.38905609893065f;    // e^2 (x-step of 1 per k)
        const float xi0 = fmaf((float)threadIdx.x, 0.00390625f,
                               0.001953125f - 4.0f);
        float e = __builtin_amdgcn_exp2f(xi0 * 2.8853900817779268f);
#pragma unroll
        for (int k = 0; k < 8; ++k) {
            lut[threadIdx.x + (k << 8)] =
                1.0f - 2.0f * __builtin_amdgcn_rcpf(e + 1.0f);
            e *= E2;
        }
    }
    __syncthreads();

    // Uniform weights (s_loads); f16 pairs built per-thread.
    h2 u[9][4];
    float w8[9], bv[9];
#pragma unroll
    for (int c = 0; c < 9; ++c) {
#pragma unroll
        for (int k = 0; k < 4; ++k)
            u[c][k] = pkrtz(W[c * 9 + 2 * k], W[c * 9 + 2 * k + 1]);
        w8[c] = W[c * 9 + 8];
        bv[c] = Bv[c];
    }

    // tanh lookup: clamp+floor index into the block-local LUT.
    auto tlu = [&](float v) -> float {
        float t = __builtin_amdgcn_fmed3f(fmaf(v, 256.0f, 1024.0f),
                                          0.0f, 2047.0f);
        return lut[(int)t];
    };

    float o[CPT];
#pragma unroll
    for (int tp = 0; tp < 4; ++tp) {
        const int t0 = 2 * tp;
        // f16 K-pairs for pixels t0 and t0+1:
        // A=(p0q0,p0q1) B=(p0q2,p1q0) C=(p1q1,p1q2) D=(p2q0,p2q1), lone p2q2 f32
        h2 A0 = pkrtz(r0[t0],     r0[t0 + 1]);
        h2 B0 = pkrtz(r0[t0 + 2], r1[t0]);
        h2 C0 = pkrtz(r1[t0 + 1], r1[t0 + 2]);
        h2 D0 = pkrtz(r2[t0],     r2[t0 + 1]);
        h2 A1 = pkrtz(r0[t0 + 1], r0[t0 + 2]);
        h2 B1 = pkrtz(r0[t0 + 3], r1[t0 + 1]);
        h2 C1 = pkrtz(r1[t0 + 2], r1[t0 + 3]);
        h2 D1 = pkrtz(r2[t0 + 1], r2[t0 + 2]);

        float ox = 0.0f, oy = 0.0f;
#pragma unroll
        for (int c = 0; c < 9; ++c) {
            float fx = bv[c], fy = bv[c];
            fx = FDOT2(A0, u[c][0], fx);
            fy = FDOT2(A1, u[c][0], fy);
            fx = FDOT2(B0, u[c][1], fx);
            fy = FDOT2(B1, u[c][1], fy);
            fx = FDOT2(C0, u[c][2], fx);
            fy = FDOT2(C1, u[c][2], fy);
            fx = FDOT2(D0, u[c][3], fx);
            fy = FDOT2(D1, u[c][3], fy);
            fx = fmaf(r2[t0 + 2], w8[c], fx);
            fy = fmaf(r2[t0 + 3], w8[c], fy);

            const float thx = tlu(fx);
            const float thy = tlu(fy);

            // tap stage: out += patch[j][i] * tanh(fc_c), c = 3i+j
            const int i = c / 3, j = c - 3 * i;
            const float* rj = (j == 0) ? r0 : (j == 1) ? r1 : r2;
            ox = fmaf(rj[t0 + i],     thx, ox);
            oy = fmaf(rj[t0 + 1 + i], thy, oy);
        }
        o[t0] = ox; o[t0 + 1] = oy;
    }

    float* orow = out + (size_t)row * IMG + x0;
    *reinterpret_cast<float4*>(orow)     = make_float4(o[0], o[1], o[2], o[3]);
    *reinterpret_cast<float4*>(orow + 4) = make_float4(o[4], o[5], o[6], o[7]);
}

extern "C" void kernel_launch(void* const* d_in, const int* in_sizes, int n_in,
                              void* d_out, int out_size, void* d_ws, size_t ws_size,
                              hipStream_t stream) {
    const float* x  = (const float*)d_in[0];   // (B,1,512,512) f32
    const float* W  = (const float*)d_in[1];   // (9,1,3,3)     f32
    const float* Bv = (const float*)d_in[2];   // (9,)          f32
    float* out = (float*)d_out;

    const int batch   = in_sizes[0] / (IMG * IMG);   // 32
    const int threads = batch * IMG * CGRP;          // 1,048,576
    const int grid    = threads / 256;               // 4096
    fused_convtap_kernel<<<grid, 256, 0, stream>>>(x, W, Bv, out);
}